// Round 1
// baseline (88681.897 us; speedup 1.0000x reference)
//
#include <hip/hip_runtime.h>

#define NWG 128
#define WGS 512

typedef __attribute__((ext_vector_type(4))) float facc4;
typedef __attribute__((ext_vector_type(8))) short bfrag8;

#define MFMA_BF16 __builtin_amdgcn_mfma_f32_16x16x32_bf16

constexpr int B_ = 128, T_ = 512, I_ = 128, H_ = 1024;
constexpr int G_ = 4 * H_;  // 4096

// ---------------- workspace layout (bytes) ----------------
constexpr size_t OFF_BAR  = 0;        // 4096 reserved (padded barrier lines)
constexpr size_t OFF_H1F  = 4096;
constexpr size_t OFF_H2F  = OFF_H1F + 2ull * B_ * H_ * 4;
constexpr size_t OFF_C1   = OFF_H2F + 2ull * B_ * H_ * 4;
constexpr size_t OFF_C2   = OFF_C1 + (size_t)B_ * H_ * 4;
constexpr size_t OFF_X1F  = OFF_C2 + (size_t)B_ * H_ * 4;
constexpr size_t OFF_X2F  = OFF_X1F + (size_t)B_ * I_ * 4;
constexpr size_t OFF_H1S  = OFF_X2F + (size_t)B_ * H_ * 4;
constexpr size_t OFF_H2S  = OFF_H1S + 2ull * B_ * H_ * 2;
constexpr size_t OFF_X1S  = OFF_H2S + 2ull * B_ * H_ * 2;
constexpr size_t OFF_X2S  = OFF_X1S + (size_t)B_ * I_ * 2;
constexpr size_t OFF_BS1  = OFF_X2S + (size_t)B_ * H_ * 2;
constexpr size_t OFF_BS2  = OFF_BS1 + (size_t)G_ * 4;
constexpr size_t ZERO_BYTES = OFF_BS2 + (size_t)G_ * 4;
// bf16 weights (converted in-kernel each launch), L2-resident
constexpr size_t OFF_WQ1  = ZERO_BYTES;                         // 3*I*H
constexpr size_t OFF_WR1  = OFF_WQ1 + 3ull * I_ * H_ * 2;       // 2*H*I
constexpr size_t OFF_WIH1 = OFF_WR1 + 2ull * H_ * I_ * 2;       // G*I
constexpr size_t OFF_WHH1 = OFF_WIH1 + (size_t)G_ * I_ * 2;     // G*H
constexpr size_t OFF_WQ2  = OFF_WHH1 + (size_t)G_ * H_ * 2;     // 3*H*H
constexpr size_t OFF_WR2  = OFF_WQ2 + 3ull * H_ * H_ * 2;       // 2*H*H
constexpr size_t OFF_WIH2 = OFF_WR2 + 2ull * H_ * H_ * 2;       // G*H
constexpr size_t OFF_WHH2 = OFF_WIH2 + (size_t)G_ * H_ * 2;     // G*H

// ---------------- dynamic LDS: one A-staging buffer ----------------
// worst case cell2: 16 rows x (1024+1024+8) bf16 = 65792 B.
// all strides are ==8 (mod 64) elements -> row stride == 16B (mod 128B):
// 8 consecutive rows cover all 32 banks; 16-row b128 reads are 2-way (free).
constexpr size_t DYN_LDS = 16ull * 2056 * 2;  // 65792

struct GBar {
  unsigned leaf[16][32];  // one counter per 128B line (de-conflict L3 atomics)
  unsigned root[32];
  unsigned gen[32];
};

__device__ __forceinline__ float sigf(float x) { return 1.0f / (1.0f + __expf(-x)); }

__device__ __forceinline__ unsigned short f2bf(float f) {
  union { float f; unsigned u; } v; v.f = f;
  unsigned r = v.u + 0x7FFFu + ((v.u >> 16) & 1u);  // RNE
  return (unsigned short)(r >> 16);
}

// ---------- device-coherent (sc0 sc1) data plane for cross-WG data ----------
__device__ __forceinline__ float cloadf(const float* p) {
  return __hip_atomic_load(p, __ATOMIC_RELAXED, __HIP_MEMORY_SCOPE_AGENT);
}
__device__ __forceinline__ void cstoref(float* p, float v) {
  __hip_atomic_store(p, v, __ATOMIC_RELAXED, __HIP_MEMORY_SCOPE_AGENT);
}
__device__ __forceinline__ void cstoreu(unsigned* p, unsigned v) {
  __hip_atomic_store(p, v, __ATOMIC_RELAXED, __HIP_MEMORY_SCOPE_AGENT);
}
// pack bf16 shadow pairs: even lane stores (v, neighbor v) as one u32
__device__ __forceinline__ void cstore_sh(unsigned short* base, size_t idx, float v, int lane) {
  float vo = __shfl_xor(v, 1);
  if (!(lane & 1)) {
    unsigned pk = (unsigned)f2bf(v) | ((unsigned)f2bf(vo) << 16);
    cstoreu((unsigned*)(base + idx), pk);
  }
}

// bulk coherent stage: rows x (C4*4) bf16 elements -> LDS (called by whole WG)
template <int C4>
__device__ __forceinline__ void stage_coh(unsigned short* lds, int ldsStride, int ldsColOff,
                                          const unsigned short* src, int srcStride, int rows) {
  const int total = rows * C4;
  for (int i = threadIdx.x; i < total; i += WGS) {
    int r = i / C4, q = (i % C4) * 4;
    unsigned long long v = __hip_atomic_load(
        (const unsigned long long*)(src + (size_t)r * srcStride + q),
        __ATOMIC_RELAXED, __HIP_MEMORY_SCOPE_AGENT);
    *(unsigned long long*)(lds + (size_t)r * ldsStride + ldsColOff + q) = v;
  }
}

// ---- fence-free device barrier. Safe because __syncthreads drains every
// wave's vmcnt (coherent stores are then at L3), and all cross-WG data is sc0/sc1.
__device__ __forceinline__ void gbar_fast(GBar* b) {
  __syncthreads();
  if (threadIdx.x == 0) {
    unsigned g = __hip_atomic_load(&b->gen[0], __ATOMIC_RELAXED, __HIP_MEMORY_SCOPE_AGENT);
    int leaf = blockIdx.x >> 3;  // 16 leaves x 8 WGs
    unsigned a = __hip_atomic_fetch_add(&b->leaf[leaf][0], 1u, __ATOMIC_RELAXED,
                                        __HIP_MEMORY_SCOPE_AGENT);
    if (a == 7u) {
      unsigned r = __hip_atomic_fetch_add(&b->root[0], 1u, __ATOMIC_RELAXED,
                                          __HIP_MEMORY_SCOPE_AGENT);
      if (r == 15u) {
        for (int i = 0; i < 16; i++)
          __hip_atomic_store(&b->leaf[i][0], 0u, __ATOMIC_RELAXED, __HIP_MEMORY_SCOPE_AGENT);
        __hip_atomic_store(&b->root[0], 0u, __ATOMIC_RELAXED, __HIP_MEMORY_SCOPE_AGENT);
        // release: leaf resets must be visible before the new generation
        __hip_atomic_store(&b->gen[0], g + 1u, __ATOMIC_RELEASE, __HIP_MEMORY_SCOPE_AGENT);
      }
    }
    while (__hip_atomic_load(&b->gen[0], __ATOMIC_RELAXED, __HIP_MEMORY_SCOPE_AGENT) == g)
      __builtin_amdgcn_s_sleep(1);
    asm volatile("" ::: "memory");
  }
  __syncthreads();
}

// ---- full-fence barrier: ONCE after init (weights are plain stores)
__device__ __forceinline__ void gbar_init(GBar* b) {
  __syncthreads();
  if (threadIdx.x == 0) {
    __builtin_amdgcn_fence(__ATOMIC_RELEASE, "agent");
    unsigned g = __hip_atomic_load(&b->gen[0], __ATOMIC_RELAXED, __HIP_MEMORY_SCOPE_AGENT);
    int leaf = blockIdx.x >> 3;
    unsigned a = __hip_atomic_fetch_add(&b->leaf[leaf][0], 1u, __ATOMIC_RELAXED,
                                        __HIP_MEMORY_SCOPE_AGENT);
    if (a == 7u) {
      unsigned r = __hip_atomic_fetch_add(&b->root[0], 1u, __ATOMIC_RELAXED,
                                          __HIP_MEMORY_SCOPE_AGENT);
      if (r == 15u) {
        for (int i = 0; i < 16; i++)
          __hip_atomic_store(&b->leaf[i][0], 0u, __ATOMIC_RELAXED, __HIP_MEMORY_SCOPE_AGENT);
        __hip_atomic_store(&b->root[0], 0u, __ATOMIC_RELAXED, __HIP_MEMORY_SCOPE_AGENT);
        __hip_atomic_store(&b->gen[0], g + 1u, __ATOMIC_RELEASE, __HIP_MEMORY_SCOPE_AGENT);
      }
    }
    while (__hip_atomic_load(&b->gen[0], __ATOMIC_RELAXED, __HIP_MEMORY_SCOPE_AGENT) == g)
      __builtin_amdgcn_s_sleep(1);
    __builtin_amdgcn_fence(__ATOMIC_ACQUIRE, "agent");
  }
  __syncthreads();
}

// ---- mogrify round: one full-K 16x16 tile per wave (no K-split, no reduce).
// WG stages its mt A-tile once; wave wv computes nt = ntBase + wv.
// acc[j] -> (m = mt*16 + lq*4 + j, n = nt*16 + l15)   [verified C/D layout]
template <int K>
__device__ __forceinline__ void mog8(
    const unsigned short* __restrict__ A,   // bf16 shadow, row stride K
    const unsigned short* __restrict__ W,   // N rows x K
    const float* __restrict__ bias,
    const float* srcF, int srcStride,
    float* dstF, unsigned short* dstS, int N,
    int mt, int ntBase, unsigned short* As) {
  const int tid = threadIdx.x;
  const int lane = tid & 63;
  const int wv = tid >> 6;
  const int l15 = lane & 15, lq = lane >> 4;
  const int nt = ntBase + wv;
  const int n = nt * 16 + l15;
  constexpr int LSTR = K + 8;

  // hoist: issue the epilogue's coherent src loads early (hide L3 latency
  // under staging + MFMA). Safe: (m,n) is lane-exclusive this phase.
  float srcv[4];
#pragma unroll
  for (int j = 0; j < 4; j++)
    srcv[j] = cloadf(&srcF[(size_t)(mt * 16 + lq * 4 + j) * srcStride + n]);
  const float bn = bias[n];

  stage_coh<K / 4>(As, LSTR, 0, A + (size_t)(mt * 16) * K, K, 16);
  __syncthreads();

  const unsigned short* ap = As + l15 * LSTR + lq * 8;
  const unsigned short* wp = W + (size_t)n * K + lq * 8;
  facc4 acc0 = {0.f, 0.f, 0.f, 0.f}, acc1 = {0.f, 0.f, 0.f, 0.f};
#pragma unroll
  for (int k = 0; k < K; k += 64) {
    acc0 = MFMA_BF16(*(const bfrag8*)(ap + k), *(const bfrag8*)(wp + k), acc0, 0, 0, 0);
    acc1 = MFMA_BF16(*(const bfrag8*)(ap + k + 32), *(const bfrag8*)(wp + k + 32), acc1, 0, 0, 0);
  }
#pragma unroll
  for (int j = 0; j < 4; j++) {
    float d = acc0[j] + acc1[j];
    float v = 2.0f * sigf(d + bn) * srcv[j];
    const int m = mt * 16 + lq * 4 + j;
    cstoref(&dstF[(size_t)m * N + n], v);
    cstore_sh(dstS, (size_t)m * N + n, v, lane);
  }
  // no trailing sync: next LDS reuse is after the global barrier's syncthreads
}

// ---- LSTM cell: one (mt, ntc) tile per wave, ALL 4 GATES in-wave
// (4 accumulator chains) -> epilogue is wave-local, no cross-wave reduce.
template <int KX>
__device__ __forceinline__ void cell_unit(
    const unsigned short* __restrict__ Xs,  // B x KX bf16
    const unsigned short* __restrict__ Hs,  // B x 1024 bf16 (mogrified h)
    const unsigned short* __restrict__ Wih, // G x KX
    const unsigned short* __restrict__ Whh, // G x 1024
    const float* __restrict__ bsum,
    float* c, float* hF, unsigned short* hS,
    int mt, int ntc, unsigned short* As) {
  constexpr int LSTR = KX + 1024 + 8;
  const int tid = threadIdx.x;
  const int lane = tid & 63;
  const int l15 = lane & 15, lq = lane >> 4;
  const int n = ntc * 16 + l15;

  // hoist coherent c-loads + bias loads ahead of staging/MFMA
  float coldv[4];
#pragma unroll
  for (int j = 0; j < 4; j++)
    coldv[j] = cloadf(&c[(size_t)(mt * 16 + lq * 4 + j) * H_ + n]);
  const float bi = bsum[n], bff = bsum[H_ + n], bg = bsum[2 * H_ + n], bo = bsum[3 * H_ + n];

  stage_coh<KX / 4>(As, LSTR, 0, Xs + (size_t)(mt * 16) * KX, KX, 16);
  stage_coh<256>(As, LSTR, KX, Hs + (size_t)(mt * 16) * 1024, 1024, 16);
  __syncthreads();

  const unsigned short* ap = As + l15 * LSTR + lq * 8;
  const unsigned short* wi = Wih + (size_t)n * KX + lq * 8;
  const unsigned short* wh = Whh + (size_t)n * 1024 + lq * 8;
  facc4 a0 = {0.f,0.f,0.f,0.f}, a1 = {0.f,0.f,0.f,0.f},
        a2 = {0.f,0.f,0.f,0.f}, a3 = {0.f,0.f,0.f,0.f};
#pragma unroll 4
  for (int k = 0; k < KX; k += 32) {
    bfrag8 af = *(const bfrag8*)(ap + k);
    a0 = MFMA_BF16(af, *(const bfrag8*)(wi + (size_t)0 * H_ * KX + k), a0, 0, 0, 0);
    a1 = MFMA_BF16(af, *(const bfrag8*)(wi + (size_t)1 * H_ * KX + k), a1, 0, 0, 0);
    a2 = MFMA_BF16(af, *(const bfrag8*)(wi + (size_t)2 * H_ * KX + k), a2, 0, 0, 0);
    a3 = MFMA_BF16(af, *(const bfrag8*)(wi + (size_t)3 * H_ * KX + k), a3, 0, 0, 0);
  }
#pragma unroll 4
  for (int k = 0; k < 1024; k += 32) {
    bfrag8 af = *(const bfrag8*)(ap + KX + k);
    a0 = MFMA_BF16(af, *(const bfrag8*)(wh + (size_t)0 * H_ * 1024 + k), a0, 0, 0, 0);
    a1 = MFMA_BF16(af, *(const bfrag8*)(wh + (size_t)1 * H_ * 1024 + k), a1, 0, 0, 0);
    a2 = MFMA_BF16(af, *(const bfrag8*)(wh + (size_t)2 * H_ * 1024 + k), a2, 0, 0, 0);
    a3 = MFMA_BF16(af, *(const bfrag8*)(wh + (size_t)3 * H_ * 1024 + k), a3, 0, 0, 0);
  }
#pragma unroll
  for (int j = 0; j < 4; j++) {
    float iv = sigf(a0[j] + bi);
    float fv = sigf(a1[j] + bff);
    float gv = tanhf(a2[j] + bg);
    float ov = sigf(a3[j] + bo);
    const int m = mt * 16 + lq * 4 + j;
    const size_t idx = (size_t)m * H_ + n;
    float cn = fv * coldv[j] + iv * gv;
    float hn = ov * tanhf(cn);
    cstoref(&c[idx], cn);
    cstoref(&hF[idx], hn);
    cstore_sh(hS, idx, hn, lane);
  }
}

__global__ __launch_bounds__(WGS, 1) void moglstm_kernel(
    const float* __restrict__ in_seq,
    const float* __restrict__ c1Q, const float* __restrict__ c1Qb,
    const float* __restrict__ c1R, const float* __restrict__ c1Rb,
    const float* __restrict__ c1Wih, const float* __restrict__ c1Whh,
    const float* __restrict__ c1bih, const float* __restrict__ c1bhh,
    const float* __restrict__ c2Q, const float* __restrict__ c2Qb,
    const float* __restrict__ c2R, const float* __restrict__ c2Rb,
    const float* __restrict__ c2Wih, const float* __restrict__ c2Whh,
    const float* __restrict__ c2bih, const float* __restrict__ c2bhh,
    const float* __restrict__ linW, const float* __restrict__ linb,
    char* ws, float* __restrict__ out) {
  extern __shared__ char dynlds[];
  unsigned short* As = (unsigned short*)dynlds;

  GBar* bar = (GBar*)(ws + OFF_BAR);
  float* h1f0 = (float*)(ws + OFF_H1F);
  float* h1f1 = h1f0 + (size_t)B_ * H_;
  float* h2f0 = (float*)(ws + OFF_H2F);
  float* h2f1 = h2f0 + (size_t)B_ * H_;
  float* c1f = (float*)(ws + OFF_C1);
  float* c2f = (float*)(ws + OFF_C2);
  float* x1f = (float*)(ws + OFF_X1F);
  float* x2f = (float*)(ws + OFF_X2F);
  unsigned short* h1s0 = (unsigned short*)(ws + OFF_H1S);
  unsigned short* h1s1 = h1s0 + (size_t)B_ * H_;
  unsigned short* h2s0 = (unsigned short*)(ws + OFF_H2S);
  unsigned short* h2s1 = h2s0 + (size_t)B_ * H_;
  unsigned short* x1s = (unsigned short*)(ws + OFF_X1S);
  unsigned short* x2s = (unsigned short*)(ws + OFF_X2S);
  float* bs1 = (float*)(ws + OFF_BS1);
  float* bs2 = (float*)(ws + OFF_BS2);
  unsigned short* wq1 = (unsigned short*)(ws + OFF_WQ1);
  unsigned short* wr1 = (unsigned short*)(ws + OFF_WR1);
  unsigned short* wih1 = (unsigned short*)(ws + OFF_WIH1);
  unsigned short* whh1 = (unsigned short*)(ws + OFF_WHH1);
  unsigned short* wq2 = (unsigned short*)(ws + OFF_WQ2);
  unsigned short* wr2 = (unsigned short*)(ws + OFF_WR2);
  unsigned short* wih2 = (unsigned short*)(ws + OFF_WIH2);
  unsigned short* whh2 = (unsigned short*)(ws + OFF_WHH2);

  const int wg = blockIdx.x;

  // ---- init: fp32 -> bf16 weight conversion (plain stores) + bias sums
  {
    size_t gt = (size_t)wg * WGS + threadIdx.x;
    const size_t gs = (size_t)NWG * WGS;
    const float* srcs[8] = {c1Q, c1R, c1Wih, c1Whh, c2Q, c2R, c2Wih, c2Whh};
    unsigned short* dsts[8] = {wq1, wr1, wih1, whh1, wq2, wr2, wih2, whh2};
    const size_t cnts[8] = {3ull * I_ * H_, 2ull * H_ * I_, (size_t)G_ * I_,
                            (size_t)G_ * H_, 3ull * H_ * H_, 2ull * H_ * H_,
                            (size_t)G_ * H_, (size_t)G_ * H_};
    for (int a = 0; a < 8; a++)
      for (size_t i = gt; i < cnts[a]; i += gs) dsts[a][i] = f2bf(srcs[a][i]);
    for (size_t i = gt; i < (size_t)G_; i += gs) bs1[i] = c1bih[i] + c1bhh[i];
    for (size_t i = gt; i < (size_t)G_; i += gs) bs2[i] = c2bih[i] + c2bhh[i];
  }
  gbar_init(bar);  // full fences ONCE: publish plain-stored weights

  // phase p runs layer-1 step t=p and layer-2 step t=p-1 concurrently.
  // 6 phases/iter: s=0..4 mogrify rounds, s=5 both LSTM cells (full-K, no reduce).
  // WGs 0..63: layer-2 mog + cell1. WGs 64..127: layer-1 mog + cell2.
  for (int p = 0; p <= T_; ++p) {
    const int q = p & 1;
    const int q2 = 1 - q;
    const bool doL1 = (p < T_);
    const bool doL2 = (p > 0);
    float* h1q = q ? h1f1 : h1f0;
    float* h1o = q ? h1f0 : h1f1;
    unsigned short* h1sq = q ? h1s1 : h1s0;
    unsigned short* h1so = q ? h1s0 : h1s1;
    float* h2q2 = q2 ? h2f1 : h2f0;
    float* h2o = q ? h2f1 : h2f0;
    unsigned short* h2sq2 = q2 ? h2s1 : h2s0;
    unsigned short* h2so = q ? h2s1 : h2s0;

    for (int s = 0; s < 6; ++s) {
      if (s < 5) {
        if (doL2 && wg < 64) {
          // layer 2, step p-1: 512 tiles = 64 WGs x 8 waves, full K=1024
          const int mt = wg >> 3, ntb = (wg & 7) * 8;
          switch (s) {
            case 0: mog8<1024>(h2sq2, wq2, c2Qb, h1q, H_, x2f, x2s, H_, mt, ntb, As); break;
            case 1: mog8<1024>(x2s, wr2, c2Rb, h2q2, H_, h2q2, h2sq2, H_, mt, ntb, As); break;
            case 2: mog8<1024>(h2sq2, wq2 + 1ull * H_ * H_, c2Qb + H_, x2f, H_, x2f, x2s, H_, mt, ntb, As); break;
            case 3: mog8<1024>(x2s, wr2 + 1ull * H_ * I_ * 8, c2Rb + H_, h2q2, H_, h2q2, h2sq2, H_, mt, ntb, As); break;
            case 4: mog8<1024>(h2sq2, wq2 + 2ull * H_ * H_, c2Qb + 2 * H_, x2f, H_, x2f, x2s, H_, mt, ntb, As); break;
          }
        } else if (doL1 && wg >= 64) {
          // layer 1, step p
          if (s == 1 || s == 3) {  // R rounds: 512 tiles = 64 WGs, K=128
            const int w1 = wg - 64;
            const int mt = w1 >> 3, ntb = (w1 & 7) * 8;
            if (s == 1) mog8<128>(x1s, wr1, c1Rb, h1q, H_, h1q, h1sq, H_, mt, ntb, As);
            else        mog8<128>(x1s, wr1 + 1ull * H_ * I_, c1Rb + H_, h1q, H_, h1q, h1sq, H_, mt, ntb, As);
          } else if (wg < 72) {    // Q rounds: 64 tiles = 8 WGs, K=1024
            const int mt = wg - 64;
            if (s == 0)      mog8<1024>(h1sq, wq1, c1Qb, in_seq + (size_t)p * I_, T_ * I_, x1f, x1s, I_, mt, 0, As);
            else if (s == 2) mog8<1024>(h1sq, wq1 + 1ull * I_ * H_, c1Qb + I_, x1f, I_, x1f, x1s, I_, mt, 0, As);
            else             mog8<1024>(h1sq, wq1 + 2ull * I_ * H_, c1Qb + 2 * I_, x1f, I_, x1f, x1s, I_, mt, 0, As);
          }
        }
      } else {  // s == 5: both cells, 4 gates per wave, wave-local epilogue
        if (doL1 && wg < 64)
          cell_unit<128>(x1s, h1sq, wih1, whh1, bs1, c1f, h1o, h1so,
                         wg >> 3, (wg & 7) * 8 + (threadIdx.x >> 6), As);
        if (doL2 && wg >= 64) {
          const int w2 = wg - 64;
          cell_unit<1024>(x2s, h2sq2, wih2, whh2, bs2, c2f, h2o, h2so,
                          w2 >> 3, (w2 & 7) * 8 + (threadIdx.x >> 6), As);
        }
      }
      gbar_fast(bar);
    }
  }

  // ---- final linear: out[b] = dot(h2_final[b,:], linW) + linb (parity 0)
  if (wg == 0) {
    float* rf = (float*)As;
    const int tid = threadIdx.x;
    const int b = tid >> 2, qq = tid & 3;
    const float* row = h2f0 + (size_t)b * H_ + qq * 256;
    const float* w = linW + qq * 256;
    float s = 0.f;
    for (int k = 0; k < 256; k++) s += cloadf(&row[k]) * w[k];
    rf[tid] = s;
    __syncthreads();
    if (tid < B_)
      out[tid] = rf[tid * 4] + rf[tid * 4 + 1] + rf[tid * 4 + 2] + rf[tid * 4 + 3] + linb[0];
  }
}

extern "C" void kernel_launch(void* const* d_in, const int* in_sizes, int n_in,
                              void* d_out, int out_size, void* d_ws, size_t ws_size,
                              hipStream_t stream) {
  const float* in_seq = (const float*)d_in[0];
  const float* c1Q = (const float*)d_in[1];
  const float* c1Qb = (const float*)d_in[2];
  const float* c1R = (const float*)d_in[3];
  const float* c1Rb = (const float*)d_in[4];
  const float* c1Wih = (const float*)d_in[5];
  const float* c1Whh = (const float*)d_in[6];
  const float* c1bih = (const float*)d_in[7];
  const float* c1bhh = (const float*)d_in[8];
  const float* c2Q = (const float*)d_in[9];
  const float* c2Qb = (const float*)d_in[10];
  const float* c2R = (const float*)d_in[11];
  const float* c2Rb = (const float*)d_in[12];
  const float* c2Wih = (const float*)d_in[13];
  const float* c2Whh = (const float*)d_in[14];
  const float* c2bih = (const float*)d_in[15];
  const float* c2bhh = (const float*)d_in[16];
  const float* linW = (const float*)d_in[17];
  const float* linb = (const float*)d_in[18];

  static_assert(DYN_LDS == 65792, "lds layout");
  hipFuncSetAttribute((const void*)moglstm_kernel,
                      hipFuncAttributeMaxDynamicSharedMemorySize, (int)DYN_LDS);
  hipMemsetAsync(d_ws, 0, ZERO_BYTES, stream);
  moglstm_kernel<<<dim3(NWG), dim3(WGS), DYN_LDS, stream>>>(
      in_seq, c1Q, c1Qb, c1R, c1Rb, c1Wih, c1Whh, c1bih, c1bhh,
      c2Q, c2Qb, c2R, c2Rb, c2Wih, c2Whh, c2bih, c2bhh,
      linW, linb, (char*)d_ws, (float*)d_out);
}